// Round 5
// baseline (144838.257 us; speedup 1.0000x reference)
//
#include <hip/hip_runtime.h>
#include <hip/hip_bf16.h>
#include <math.h>

// Problem constants
#define T_STEPS 8192
#define HDIM    1024
#define GWS       32    // relay WGs (elected, co-resident on ONE XCD), 1024 thr each
#define SCAN_GRID 512   // launched WGs; losers of the election exit
#define NSLOT     512   // slot k = {h[2k], h[2k+1], pad, tag} (16 B, self-tagged)

// Workspace layout (bytes)
#define OFF_REV   ((size_t)0)                         // 8192*64*4   = 2 MB
#define OFF_X1    ((size_t)2097152)                   // 8192*512*4  = 16 MB (reused as slots+ctrl after gemm2)
#define OFF_B     ((size_t)18874368)                  // x2 then hs: 8192*1024*4 = 32 MB
#define OFF_C     ((size_t)52428800)                  // xp then y1: 8192*3072*4 = 96 MB
#define OFF_CTRL  (OFF_X1 + 32768)                    // 32 ints of election state
#define WS_NEEDED ((size_t)153092096)

typedef float f4 __attribute__((ext_vector_type(4)));

__device__ inline float sigm(float x)   { return 1.0f / (1.0f + __expf(-x)); }
__device__ inline float tanh_f(float x) { float e = __expf(2.0f * x); return 1.0f - 2.0f / (e + 1.0f); }

// MALL-coherent store (seed/control path).
__device__ inline void store_cohr(f4* p, f4 v) {
    asm volatile("global_store_dwordx4 %0, %1, off sc0 sc1"
                 :: "v"(p), "v"(v) : "memory");
}

// Relay publish: FIRST store sc0 -> write-back into the XCD-shared L2
// (L1 is write-through, so the line in L2 is UPDATED -- this is the line
// same-XCD consumers' sc0 polls hit). SECOND store sc0 sc1 -> MALL truth,
// guarantees progress for the every-8th sc1 fallback poll (R4 lesson:
// sc1 write-through alone does NOT refresh stale L2 copies; sc0-only
// store alone could strand data dirty in L2 w.r.t. MALL).
__device__ inline void publish_slot(f4* p, f4 v) {
    asm volatile("global_store_dwordx4 %0, %1, off sc0\n\t"
                 "global_store_dwordx4 %0, %1, off sc0 sc1"
                 :: "v"(p), "v"(v) : "memory");
}

// Single-slot poll: sc0 loads hit the leader XCD's L2 (fast path, ~L2 RT);
// every 8th round reads sc0 sc1 (MALL) as the guaranteed-progress net.
// s_sleep(1) throttles L2 read pressure (R2 lesson).
__device__ inline f4 poll_slot(const f4* p, unsigned want) {
    int r = 0;
    for (;;) {
        f4 v;
        if ((++r & 7) == 0) {
            asm volatile("global_load_dwordx4 %0, %1, off sc0 sc1\n\ts_waitcnt vmcnt(0)"
                         : "=v"(v) : "v"(p) : "memory");
        } else {
            asm volatile("global_load_dwordx4 %0, %1, off sc0\n\ts_waitcnt vmcnt(0)"
                         : "=v"(v) : "v"(p) : "memory");
        }
        if (__float_as_uint(v.w) == want) return v;
        __builtin_amdgcn_s_sleep(1);
    }
}

// ---------------------------------------------------------------------------
// Election: first XCD to accumulate GWS registrants becomes leader; its first
// GWS registrants take roles 0..GWS-1 (co-resident by construction: all are
// mid-spin when the GWS-th registers). Everyone else exits.
// ctrl: [0..7]=per-XCD count, [8]=leader (-1 init). Device-scope atomics.
// ---------------------------------------------------------------------------
__device__ inline int elect_role(int* ctrl) {
    unsigned xcc;
    asm volatile("s_getreg_b32 %0, hwreg(HW_REG_XCC_ID)" : "=s"(xcc));
    xcc &= 7u;
    int idx = atomicAdd(&ctrl[xcc], 1);
    if (idx == GWS - 1) atomicCAS(&ctrl[8], -1, (int)xcc);
    if (idx >= GWS) return -1;
    int ld;
    do {
        __builtin_amdgcn_s_sleep(2);
        asm volatile("global_load_dword %0, %1, off sc0 sc1\n\ts_waitcnt vmcnt(0)"
                     : "=v"(ld) : "v"(ctrl + 8) : "memory");
    } while (ld == -1);   // terminates: some XCD reaches GWS (pigeonhole)
    return (ld == (int)xcc) ? idx : -1;
}

// ---------------------------------------------------------------------------
// build rev: rev[t][0:32]=weather[T-1-t], rev[t][32:64]=infect[T-1-t]
// ---------------------------------------------------------------------------
__global__ void build_rev(const float* __restrict__ wea, const float* __restrict__ inf,
                          float* __restrict__ rev) {
    int idx = blockIdx.x * blockDim.x + threadIdx.x;   // over T*64
    if (idx >= T_STEPS * 64) return;
    int t = idx >> 6, c = idx & 63;
    int ts = T_STEPS - 1 - t;
    rev[idx] = (c < 32) ? wea[ts * 32 + c] : inf[ts * 32 + (c - 32)];
}

// ---------------------------------------------------------------------------
// seed slots (both tag buffers) with h_init / poison, reset election state
// ---------------------------------------------------------------------------
__global__ void seed_slots(const float* __restrict__ h0, f4* __restrict__ slots,
                           int* __restrict__ ctrl) {
    int i = blockIdx.x * blockDim.x + threadIdx.x;   // grid covers 2*NSLOT
    if (i < NSLOT) {
        f4 v;
        v.x = h0[2 * i]; v.y = h0[2 * i + 1]; v.z = 0.0f;
        v.w = __uint_as_float(0u);
        store_cohr(&slots[i], v);
    } else if (i < 2 * NSLOT) {
        f4 v;
        v.x = 0.f; v.y = 0.f; v.z = 0.f;
        v.w = __uint_as_float(0xFFFFFFFFu);          // poison tag
        store_cohr(&slots[i], v);
    }
    if (blockIdx.x == 0 && threadIdx.x < 32) {
        int v = (threadIdx.x == 8 || threadIdx.x == 24) ? -1 : 0;
        asm volatile("global_store_dword %0, %1, off sc0 sc1"
                     :: "v"(ctrl + threadIdx.x), "v"(v) : "memory");
    }
}

// ---------------------------------------------------------------------------
// Tiled f32 GEMM: C[M,N] = act(A[M,K] @ W[N,K]^T + bias[N]); BM=BN=64, BK=32
// ---------------------------------------------------------------------------
__global__ __launch_bounds__(256) void gemm_bias_act(
    const float* __restrict__ A, const float* __restrict__ W,
    const float* __restrict__ bias, float* __restrict__ C,
    int M, int N, int K, int relu)
{
    __shared__ float As[32][68];
    __shared__ float Ws[32][68];
    const int tid = threadIdx.x;
    const int tx = tid & 15, ty = tid >> 4;
    const int bm = blockIdx.y, bn = blockIdx.x;
    const float* Ab = A + (size_t)bm * 64 * K;
    const float* Wb = W + (size_t)bn * 64 * K;
    float acc[4][4] = {};

    for (int k0 = 0; k0 < K; k0 += 32) {
#pragma unroll
        for (int q = 0; q < 2; ++q) {
            int idx = tid * 2 + q;           // 0..511
            int row = idx >> 3;              // 0..63
            int kc  = (idx & 7) << 2;        // 0..28
            float4 av = *(const float4*)(Ab + (size_t)row * K + k0 + kc);
            As[kc + 0][row] = av.x; As[kc + 1][row] = av.y;
            As[kc + 2][row] = av.z; As[kc + 3][row] = av.w;
            float4 wv = *(const float4*)(Wb + (size_t)row * K + k0 + kc);
            Ws[kc + 0][row] = wv.x; Ws[kc + 1][row] = wv.y;
            Ws[kc + 2][row] = wv.z; Ws[kc + 3][row] = wv.w;
        }
        __syncthreads();
#pragma unroll
        for (int k = 0; k < 32; ++k) {
            float4 a = *(const float4*)&As[k][ty << 2];
            float4 b = *(const float4*)&Ws[k][tx << 2];
            acc[0][0] += a.x*b.x; acc[0][1] += a.x*b.y; acc[0][2] += a.x*b.z; acc[0][3] += a.x*b.w;
            acc[1][0] += a.y*b.x; acc[1][1] += a.y*b.y; acc[1][2] += a.y*b.z; acc[1][3] += a.y*b.w;
            acc[2][0] += a.z*b.x; acc[2][1] += a.z*b.y; acc[2][2] += a.z*b.z; acc[2][3] += a.z*b.w;
            acc[3][0] += a.w*b.x; acc[3][1] += a.w*b.y; acc[3][2] += a.w*b.z; acc[3][3] += a.w*b.w;
        }
        __syncthreads();
    }

    int m0 = bm * 64 + (ty << 2), n0 = bn * 64 + (tx << 2);
    float4 bv = *(const float4*)(bias + n0);
#pragma unroll
    for (int r = 0; r < 4; ++r) {
        float4 o;
        o.x = acc[r][0] + bv.x; o.y = acc[r][1] + bv.y;
        o.z = acc[r][2] + bv.z; o.w = acc[r][3] + bv.w;
        if (relu) {
            o.x = fmaxf(o.x, 0.f); o.y = fmaxf(o.y, 0.f);
            o.z = fmaxf(o.z, 0.f); o.w = fmaxf(o.w, 0.f);
        }
        *(float4*)(C + (size_t)(m0 + r) * N + n0) = o;
    }
}

// ---------------------------------------------------------------------------
// GRU scan. 32 elected WGs (one XCD) x 1024 thr; wave wv=g*16+w owns
// h[2wv], h[2wv+1] (R1's proven 2-comp/wave split). Threads tid<512 each
// poll ONE slot via the L2 fast path. Weights pinned in VGPRs.
// Tags: read tag t from slots[t&1], publish tag t+1 into slots[(t+1)&1].
// ---------------------------------------------------------------------------
__global__ __launch_bounds__(1024, 4) void gru_scan(
    const float* __restrict__ whh,   // 3072x1024
    const float* __restrict__ bhh,   // 3072
    const float* __restrict__ xp,    // 8192x3072 (includes bih)
    f4* __restrict__ slots,          // [2][NSLOT]
    float* __restrict__ hs,          // 8192x1024; hs[0]=h_enc written at end
    int* __restrict__ ctrl)          // election state (ints 0..8)
{
    __shared__ float h_sh[2][HDIM];
    __shared__ int role_sh;
    const int tid = threadIdx.x;
    if (tid == 0) role_sh = elect_role(ctrl);
    __syncthreads();
    const int g = role_sh;
    if (g < 0) return;

    const int w = tid >> 6, l = tid & 63;
    const int wv = g * 16 + w;       // 0..511
    const int iA = 2 * wv, iB = iA + 1;
    const int rows[6] = { iA, HDIM + iA, 2*HDIM + iA, iB, HDIM + iB, 2*HDIM + iB };

    // weights -> VGPRs: lane l holds w[row][256j + 4l .. +3]
    f4 Wf[6][4];
#pragma unroll
    for (int r = 0; r < 6; ++r) {
        const float* wr = whh + (size_t)rows[r] * HDIM + 4 * l;
#pragma unroll
        for (int j = 0; j < 4; ++j) Wf[r][j] = *(const f4*)(wr + 256 * j);
    }
#pragma unroll
    for (int r = 0; r < 6; ++r)
#pragma unroll
        for (int j = 0; j < 4; ++j)
            asm volatile("" : "+v"(Wf[r][j]));   // pin: opaque def, cannot remat

    // per-output constants on lanes 0 (output iA) and 1 (output iB)
    float b0 = 0.f, b1 = 0.f, b2 = 0.f;
    float xv0 = 0.f, xv1 = 0.f, xv2 = 0.f;
    int xrow = (l == 0) ? iA : iB;
    if (l < 2) {
        b0 = bhh[xrow]; b1 = bhh[HDIM + xrow]; b2 = bhh[2*HDIM + xrow];
        xv0 = xp[xrow]; xv1 = xp[HDIM + xrow]; xv2 = xp[2*HDIM + xrow];
    }

    for (int t = 0; t < T_STEPS; ++t) {
        const int buf = t & 1;
        if (tid < NSLOT) {
            f4 sa = poll_slot(slots + (size_t)buf * NSLOT + tid, (unsigned)t);
            h_sh[buf][2*tid + 0] = sa.x; h_sh[buf][2*tid + 1] = sa.y;
        }
        __syncthreads();

        f4 h4[4];
#pragma unroll
        for (int j = 0; j < 4; ++j) h4[j] = *(const f4*)&h_sh[buf][256*j + 4*l];

        float red[6];
#pragma unroll
        for (int r = 0; r < 6; ++r) {
            f4 p = Wf[r][0]*h4[0] + Wf[r][1]*h4[1] + Wf[r][2]*h4[2] + Wf[r][3]*h4[3];
            float v = p.x + p.y + p.z + p.w;
#pragma unroll
            for (int off = 32; off > 0; off >>= 1) v += __shfl_xor(v, off, 64);
            red[r] = v;
        }

        // gate math: lane0 -> output iA, lane1 -> output iB
        float hn = 0.f;
        if (l < 2) {
            float rd0 = (l == 0) ? red[0] : red[3];
            float rd1 = (l == 0) ? red[1] : red[4];
            float rd2 = (l == 0) ? red[2] : red[5];
            float hh_r = rd0 + b0, hh_z = rd1 + b1, hh_n = rd2 + b2;
            float r_ = sigm(xv0 + hh_r);
            float z_ = sigm(xv1 + hh_z);
            float n_ = tanh_f(xv2 + r_ * hh_n);
            float hp = h_sh[buf][xrow];
            hn = (1.0f - z_) * n_ + z_ * hp;
        }
        float hBv = __shfl(hn, 1, 64);
        if (l == 0) {
            unsigned pub = (unsigned)(t + 1);
            f4 s; s.x = hn; s.y = hBv; s.z = 0.0f; s.w = __uint_as_float(pub);
            publish_slot(slots + (size_t)(pub & 1) * NSLOT + wv, s);
            if (t == T_STEPS - 1) { hs[iA] = hn; hs[iB] = hBv; }
        }
        // prefetch next xp (off critical path; lands during next poll)
        if (l < 2 && t + 1 < T_STEPS) {
            const float* xq = xp + (size_t)(t + 1) * (3 * HDIM);
            xv0 = xq[xrow]; xv1 = xq[HDIM + xrow]; xv2 = xq[2*HDIM + xrow];
        }
    }
}

// ---------------------------------------------------------------------------
// LSTM-like decoder scan: h_new = o*tanh(i*g); forget rows [H,2H) are dead.
// Continues the tag sequence: reads tag 8191+s, publishes 8192+s.
// Same elected-XCD relay as gru_scan (own election state at ctrl+16).
// Cross-kernel slot handoff (gru tag 8192 -> lstm) rides the kernel-boundary
// L2 flush: gru completes before lstm launches (same stream).
// ---------------------------------------------------------------------------
__global__ __launch_bounds__(1024, 4) void lstm_scan(
    const float* __restrict__ wih,   // 4096x1024
    const float* __restrict__ bih,   // 4096
    const float* __restrict__ bhh,   // 4096
    f4* __restrict__ slots,          // [2][NSLOT]
    float* __restrict__ hs,          // 8192x1024; write hs[1..T-1]
    int* __restrict__ ctrl)          // election state (ints 16..24)
{
    __shared__ float h_sh[2][HDIM];
    __shared__ int role_sh;
    const int tid = threadIdx.x;
    if (tid == 0) role_sh = elect_role(ctrl + 16);
    __syncthreads();
    const int g = role_sh;
    if (g < 0) return;

    const int w = tid >> 6, l = tid & 63;
    const int wv = g * 16 + w;
    const int iA = 2 * wv, iB = iA + 1;
    const int rows[6] = { iA, 2*HDIM + iA, 3*HDIM + iA, iB, 2*HDIM + iB, 3*HDIM + iB };

    f4 Wf[6][4];
#pragma unroll
    for (int r = 0; r < 6; ++r) {
        const float* wr = wih + (size_t)rows[r] * HDIM + 4 * l;
#pragma unroll
        for (int j = 0; j < 4; ++j) Wf[r][j] = *(const f4*)(wr + 256 * j);
    }
#pragma unroll
    for (int r = 0; r < 6; ++r)
#pragma unroll
        for (int j = 0; j < 4; ++j)
            asm volatile("" : "+v"(Wf[r][j]));

    float b0 = 0.f, b1 = 0.f, b2 = 0.f;
    int xrow = (l == 0) ? iA : iB;
    if (l < 2) {
        b0 = bih[xrow]          + bhh[xrow];
        b1 = bih[2*HDIM + xrow] + bhh[2*HDIM + xrow];
        b2 = bih[3*HDIM + xrow] + bhh[3*HDIM + xrow];
    }

    for (int s = 1; s < T_STEPS; ++s) {
        const unsigned want = (unsigned)(8191 + s);
        const unsigned pub  = (unsigned)(8192 + s);
        const int buf = (int)(want & 1);
        if (tid < NSLOT) {
            f4 sa = poll_slot(slots + (size_t)buf * NSLOT + tid, want);
            h_sh[buf][2*tid + 0] = sa.x; h_sh[buf][2*tid + 1] = sa.y;
        }
        __syncthreads();

        f4 h4[4];
#pragma unroll
        for (int j = 0; j < 4; ++j) h4[j] = *(const f4*)&h_sh[buf][256*j + 4*l];

        float red[6];
#pragma unroll
        for (int r = 0; r < 6; ++r) {
            f4 p = Wf[r][0]*h4[0] + Wf[r][1]*h4[1] + Wf[r][2]*h4[2] + Wf[r][3]*h4[3];
            float v = p.x + p.y + p.z + p.w;
#pragma unroll
            for (int off = 32; off > 0; off >>= 1) v += __shfl_xor(v, off, 64);
            red[r] = v;
        }

        float hn = 0.f;
        if (l < 2) {
            float rd0 = (l == 0) ? red[0] : red[3];
            float rd1 = (l == 0) ? red[1] : red[4];
            float rd2 = (l == 0) ? red[2] : red[5];
            float i_ = sigm(rd0 + b0);
            float g_ = tanh_f(rd1 + b1);
            float o_ = sigm(rd2 + b2);
            hn = o_ * tanh_f(i_ * g_);
        }
        float hBv = __shfl(hn, 1, 64);
        if (l == 0) {
            f4 sv; sv.x = hn; sv.y = hBv; sv.z = 0.0f; sv.w = __uint_as_float(pub);
            publish_slot(slots + (size_t)(pub & 1) * NSLOT + wv, sv);
            hs[(size_t)s * HDIM + iA] = hn;
            hs[(size_t)s * HDIM + iB] = hBv;
        }
    }
}

// ---------------------------------------------------------------------------
// Final tiny GEMM: out[t][0:8] = y1[t] @ dec_w2^T + dec_b2, one wave per t
// ---------------------------------------------------------------------------
__global__ __launch_bounds__(256) void dec2_kernel(
    const float* __restrict__ y1,    // 8192x512
    const float* __restrict__ w2,    // 8x512
    const float* __restrict__ b2,    // 8
    float* __restrict__ out)         // 8192x8
{
    const int w = threadIdx.x >> 6, l = threadIdx.x & 63;
    const int t = blockIdx.x * 4 + w;
    const float* yr = y1 + (size_t)t * 512;
    float yv[8];
#pragma unroll
    for (int j = 0; j < 8; ++j) yv[j] = yr[l + 64 * j];
    float o[8];
#pragma unroll
    for (int n = 0; n < 8; ++n) {
        const float* wr = w2 + n * 512;
        float s = 0.f;
#pragma unroll
        for (int j = 0; j < 8; ++j) s += yv[j] * wr[l + 64 * j];
#pragma unroll
        for (int off = 32; off > 0; off >>= 1) s += __shfl_xor(s, off, 64);
        o[n] = s;
    }
    if (l == 0) {
#pragma unroll
        for (int n = 0; n < 8; ++n) out[(size_t)t * 8 + n] = o[n] + b2[n];
    }
}

// ---------------------------------------------------------------------------
extern "C" void kernel_launch(void* const* d_in, const int* in_sizes, int n_in,
                              void* d_out, int out_size, void* d_ws, size_t ws_size,
                              hipStream_t stream)
{
    const float* wea      = (const float*)d_in[0];
    const float* inf      = (const float*)d_in[1];
    const float* h_init   = (const float*)d_in[3];
    const float* enc_w1   = (const float*)d_in[4];
    const float* enc_b1   = (const float*)d_in[5];
    const float* enc_w2   = (const float*)d_in[6];
    const float* enc_b2   = (const float*)d_in[7];
    const float* gru_wih  = (const float*)d_in[8];
    const float* gru_whh  = (const float*)d_in[9];
    const float* gru_bih  = (const float*)d_in[10];
    const float* gru_bhh  = (const float*)d_in[11];
    const float* lstm_wih = (const float*)d_in[12];
    const float* lstm_bih = (const float*)d_in[13];
    const float* lstm_bhh = (const float*)d_in[14];
    const float* dec_w1   = (const float*)d_in[15];
    const float* dec_b1   = (const float*)d_in[16];
    const float* dec_w2   = (const float*)d_in[17];
    const float* dec_b2   = (const float*)d_in[18];

    if (ws_size < WS_NEEDED) return;

    char* ws = (char*)d_ws;
    float* rev   = (float*)(ws + OFF_REV);
    float* x1    = (float*)(ws + OFF_X1);
    float* x2    = (float*)(ws + OFF_B);    // later reused as hs
    float* hs    = (float*)(ws + OFF_B);
    float* xp    = (float*)(ws + OFF_C);    // later reused as y1
    float* y1    = (float*)(ws + OFF_C);
    f4*    slots = (f4*)(ws + OFF_X1);      // x1 is dead after gemm2; 16 KB
    int*   ctrl  = (int*)(ws + OFF_CTRL);   // election state, also in dead x1

    build_rev<<<(T_STEPS * 64) / 256, 256, 0, stream>>>(wea, inf, rev);

    // encoder
    gemm_bias_act<<<dim3(8, 128), 256, 0, stream>>>(rev, enc_w1, enc_b1, x1,
                                                    T_STEPS, 512, 64, 1);
    gemm_bias_act<<<dim3(16, 128), 256, 0, stream>>>(x1, enc_w2, enc_b2, x2,
                                                     T_STEPS, 1024, 512, 1);
    // GRU input projection xp = x2 @ gru_wih^T + gru_bih
    gemm_bias_act<<<dim3(48, 128), 256, 0, stream>>>(x2, gru_wih, gru_bih, xp,
                                                     T_STEPS, 3 * HDIM, HDIM, 0);
    // seed slot buffers + election state (x1 region is now dead), run scans
    seed_slots<<<4, 256, 0, stream>>>(h_init, slots, ctrl);
    gru_scan<<<SCAN_GRID, 1024, 0, stream>>>(gru_whh, gru_bhh, xp, slots, hs, ctrl);
    lstm_scan<<<SCAN_GRID, 1024, 0, stream>>>(lstm_wih, lstm_bih, lstm_bhh, slots, hs, ctrl);

    // decoder
    gemm_bias_act<<<dim3(8, 128), 256, 0, stream>>>(hs, dec_w1, dec_b1, y1,
                                                    T_STEPS, 512, HDIM, 1);
    dec2_kernel<<<T_STEPS / 4, 256, 0, stream>>>(y1, dec_w2, dec_b2, (float*)d_out);
}

// Round 6
// 56257.941 us; speedup vs baseline: 2.5745x; 2.5745x over previous
//
#include <hip/hip_runtime.h>
#include <hip/hip_bf16.h>
#include <math.h>

// Problem constants
#define T_STEPS 8192
#define HDIM    1024
#define GW      64      // scan workgroups (512 thr each; 512 producer waves total)
#define NSLOT   512     // slot k = {h[2k], h[2k+1], pad, tag} (16 B, self-tagged)

// Workspace layout (bytes)
#define OFF_REV   ((size_t)0)                         // 8192*64*4   = 2 MB
#define OFF_X1    ((size_t)2097152)                   // 8192*512*4  = 16 MB (reused as slots after gemm2)
#define OFF_B     ((size_t)18874368)                  // x2 then hs: 8192*1024*4 = 32 MB
#define OFF_C     ((size_t)52428800)                  // xp then y1: 8192*3072*4 = 96 MB
#define WS_NEEDED ((size_t)153092096)

typedef float f4 __attribute__((ext_vector_type(4)));

__device__ inline float sigm(float x)   { return 1.0f / (1.0f + __expf(-x)); }
__device__ inline float tanh_f(float x) { float e = __expf(2.0f * x); return 1.0f - 2.0f / (e + 1.0f); }

// Device-coherent (L1+L2-bypassing) 16B store: tag travels with data in one
// transaction. MALL is the only coherence point that works (R4/R5 lesson:
// remote stores never refresh another L2's stale line, so sc0-only polling
// is unsound on gfx950).
__device__ inline void store_cohr(f4* p, f4 v) {
    asm volatile("global_store_dwordx4 %0, %1, off sc0 sc1"
                 :: "v"(p), "v"(v) : "memory");
}

// Single-slot poll: one coherent 16B load, one wait, tag check.
// s_sleep(1) throttles MALL read pressure between rounds (R2 lesson).
__device__ inline f4 poll_slot(const f4* p, unsigned want) {
    for (;;) {
        f4 v;
        asm volatile("global_load_dwordx4 %0, %1, off sc0 sc1\n\ts_waitcnt vmcnt(0)"
                     : "=v"(v) : "v"(p) : "memory");
        if (__float_as_uint(v.w) == want) return v;
        __builtin_amdgcn_s_sleep(1);
    }
}

// ---------------------------------------------------------------------------
// build rev: rev[t][0:32]=weather[T-1-t], rev[t][32:64]=infect[T-1-t]
// ---------------------------------------------------------------------------
__global__ void build_rev(const float* __restrict__ wea, const float* __restrict__ inf,
                          float* __restrict__ rev) {
    int idx = blockIdx.x * blockDim.x + threadIdx.x;   // over T*64
    if (idx >= T_STEPS * 64) return;
    int t = idx >> 6, c = idx & 63;
    int ts = T_STEPS - 1 - t;
    rev[idx] = (c < 32) ? wea[ts * 32 + c] : inf[ts * 32 + (c - 32)];
}

// ---------------------------------------------------------------------------
// seed slots: buffer 0 with h_init (tag 0), buffer 1 with poison tag
// (prevents garbage float bits in dead-x1 memory from aliasing a real tag)
// ---------------------------------------------------------------------------
__global__ void seed_slots(const float* __restrict__ h0, f4* __restrict__ slots) {
    int i = blockIdx.x * blockDim.x + threadIdx.x;   // grid covers 2*NSLOT
    if (i < NSLOT) {
        f4 v;
        v.x = h0[2 * i]; v.y = h0[2 * i + 1]; v.z = 0.0f;
        v.w = __uint_as_float(0u);
        store_cohr(&slots[i], v);
    } else if (i < 2 * NSLOT) {
        f4 v;
        v.x = 0.f; v.y = 0.f; v.z = 0.f;
        v.w = __uint_as_float(0xFFFFFFFFu);          // poison tag
        store_cohr(&slots[i], v);
    }
}

// ---------------------------------------------------------------------------
// Tiled f32 GEMM: C[M,N] = act(A[M,K] @ W[N,K]^T + bias[N]); BM=BN=64, BK=32
// ---------------------------------------------------------------------------
__global__ __launch_bounds__(256) void gemm_bias_act(
    const float* __restrict__ A, const float* __restrict__ W,
    const float* __restrict__ bias, float* __restrict__ C,
    int M, int N, int K, int relu)
{
    __shared__ float As[32][68];
    __shared__ float Ws[32][68];
    const int tid = threadIdx.x;
    const int tx = tid & 15, ty = tid >> 4;
    const int bm = blockIdx.y, bn = blockIdx.x;
    const float* Ab = A + (size_t)bm * 64 * K;
    const float* Wb = W + (size_t)bn * 64 * K;
    float acc[4][4] = {};

    for (int k0 = 0; k0 < K; k0 += 32) {
#pragma unroll
        for (int q = 0; q < 2; ++q) {
            int idx = tid * 2 + q;           // 0..511
            int row = idx >> 3;              // 0..63
            int kc  = (idx & 7) << 2;        // 0..28
            float4 av = *(const float4*)(Ab + (size_t)row * K + k0 + kc);
            As[kc + 0][row] = av.x; As[kc + 1][row] = av.y;
            As[kc + 2][row] = av.z; As[kc + 3][row] = av.w;
            float4 wv = *(const float4*)(Wb + (size_t)row * K + k0 + kc);
            Ws[kc + 0][row] = wv.x; Ws[kc + 1][row] = wv.y;
            Ws[kc + 2][row] = wv.z; Ws[kc + 3][row] = wv.w;
        }
        __syncthreads();
#pragma unroll
        for (int k = 0; k < 32; ++k) {
            float4 a = *(const float4*)&As[k][ty << 2];
            float4 b = *(const float4*)&Ws[k][tx << 2];
            acc[0][0] += a.x*b.x; acc[0][1] += a.x*b.y; acc[0][2] += a.x*b.z; acc[0][3] += a.x*b.w;
            acc[1][0] += a.y*b.x; acc[1][1] += a.y*b.y; acc[1][2] += a.y*b.z; acc[1][3] += a.y*b.w;
            acc[2][0] += a.z*b.x; acc[2][1] += a.z*b.y; acc[2][2] += a.z*b.z; acc[2][3] += a.z*b.w;
            acc[3][0] += a.w*b.x; acc[3][1] += a.w*b.y; acc[3][2] += a.w*b.z; acc[3][3] += a.w*b.w;
        }
        __syncthreads();
    }

    int m0 = bm * 64 + (ty << 2), n0 = bn * 64 + (tx << 2);
    float4 bv = *(const float4*)(bias + n0);
#pragma unroll
    for (int r = 0; r < 4; ++r) {
        float4 o;
        o.x = acc[r][0] + bv.x; o.y = acc[r][1] + bv.y;
        o.z = acc[r][2] + bv.z; o.w = acc[r][3] + bv.w;
        if (relu) {
            o.x = fmaxf(o.x, 0.f); o.y = fmaxf(o.y, 0.f);
            o.z = fmaxf(o.z, 0.f); o.w = fmaxf(o.w, 0.f);
        }
        *(float4*)(C + (size_t)(m0 + r) * N + n0) = o;
    }
}

// ---------------------------------------------------------------------------
// GRU scan. 64 WGs x 512 thr (8 waves); wave wv=g*8+w owns h[2wv],h[2wv+1]
// (R1's proven compute split). Each thread polls ONE slot -> half the
// device-wide poll traffic of the 128-WG version at identical per-slot
// coverage. Weights pinned in VGPRs. Tag-in-data slot protocol, no fences.
// Tags: read tag t from slots[t&1], publish tag t+1 into slots[(t+1)&1].
// ---------------------------------------------------------------------------
__global__ __launch_bounds__(512, 1) void gru_scan(
    const float* __restrict__ whh,   // 3072x1024
    const float* __restrict__ bhh,   // 3072
    const float* __restrict__ xp,    // 8192x3072 (includes bih)
    f4* __restrict__ slots,          // [2][NSLOT]
    float* __restrict__ hs)          // 8192x1024; hs[0]=h_enc written at end
{
    __shared__ float h_sh[2][HDIM];
    const int g = blockIdx.x, tid = threadIdx.x;
    const int w = tid >> 6, l = tid & 63;
    const int wv = g * 8 + w;        // 0..511
    const int iA = 2 * wv, iB = iA + 1;
    const int rows[6] = { iA, HDIM + iA, 2*HDIM + iA, iB, HDIM + iB, 2*HDIM + iB };

    // weights -> VGPRs: lane l holds w[row][256j + 4l .. +3]
    f4 Wf[6][4];
#pragma unroll
    for (int r = 0; r < 6; ++r) {
        const float* wr = whh + (size_t)rows[r] * HDIM + 4 * l;
#pragma unroll
        for (int j = 0; j < 4; ++j) Wf[r][j] = *(const f4*)(wr + 256 * j);
    }
#pragma unroll
    for (int r = 0; r < 6; ++r)
#pragma unroll
        for (int j = 0; j < 4; ++j)
            asm volatile("" : "+v"(Wf[r][j]));   // pin: opaque def, cannot remat

    // per-output constants on lanes 0 (output iA) and 1 (output iB)
    float b0 = 0.f, b1 = 0.f, b2 = 0.f;
    float xv0 = 0.f, xv1 = 0.f, xv2 = 0.f;
    int xrow = (l == 0) ? iA : iB;
    if (l < 2) {
        b0 = bhh[xrow]; b1 = bhh[HDIM + xrow]; b2 = bhh[2*HDIM + xrow];
        xv0 = xp[xrow]; xv1 = xp[HDIM + xrow]; xv2 = xp[2*HDIM + xrow];
    }

    for (int t = 0; t < T_STEPS; ++t) {
        const int buf = t & 1;
        // each thread polls its ONE slot (h[2tid], h[2tid+1])
        f4 sa = poll_slot(slots + (size_t)buf * NSLOT + tid, (unsigned)t);
        h_sh[buf][2*tid + 0] = sa.x; h_sh[buf][2*tid + 1] = sa.y;
        __syncthreads();

        f4 h4[4];
#pragma unroll
        for (int j = 0; j < 4; ++j) h4[j] = *(const f4*)&h_sh[buf][256*j + 4*l];

        float red[6];
#pragma unroll
        for (int r = 0; r < 6; ++r) {
            f4 p = Wf[r][0]*h4[0] + Wf[r][1]*h4[1] + Wf[r][2]*h4[2] + Wf[r][3]*h4[3];
            float v = p.x + p.y + p.z + p.w;
#pragma unroll
            for (int off = 32; off > 0; off >>= 1) v += __shfl_xor(v, off, 64);
            red[r] = v;
        }

        // gate math: lane0 -> output iA, lane1 -> output iB
        float hn = 0.f;
        if (l < 2) {
            float rd0 = (l == 0) ? red[0] : red[3];
            float rd1 = (l == 0) ? red[1] : red[4];
            float rd2 = (l == 0) ? red[2] : red[5];
            float hh_r = rd0 + b0, hh_z = rd1 + b1, hh_n = rd2 + b2;
            float r_ = sigm(xv0 + hh_r);
            float z_ = sigm(xv1 + hh_z);
            float n_ = tanh_f(xv2 + r_ * hh_n);
            float hp = h_sh[buf][xrow];
            hn = (1.0f - z_) * n_ + z_ * hp;
        }
        float hBv = __shfl(hn, 1, 64);
        if (l == 0) {
            unsigned pub = (unsigned)(t + 1);
            f4 s; s.x = hn; s.y = hBv; s.z = 0.0f; s.w = __uint_as_float(pub);
            store_cohr(slots + (size_t)(pub & 1) * NSLOT + wv, s);
            if (t == T_STEPS - 1) { hs[iA] = hn; hs[iB] = hBv; }
        }
        // prefetch next xp (off critical path; lands during next poll)
        if (l < 2 && t + 1 < T_STEPS) {
            const float* xq = xp + (size_t)(t + 1) * (3 * HDIM);
            xv0 = xq[xrow]; xv1 = xq[HDIM + xrow]; xv2 = xq[2*HDIM + xrow];
        }
    }
}

// ---------------------------------------------------------------------------
// LSTM-like decoder scan: h_new = o*tanh(i*g); forget rows [H,2H) are dead.
// Continues the tag sequence: reads tag 8191+s, publishes 8192+s.
// Same 64x512 layout as gru_scan.
// ---------------------------------------------------------------------------
__global__ __launch_bounds__(512, 1) void lstm_scan(
    const float* __restrict__ wih,   // 4096x1024
    const float* __restrict__ bih,   // 4096
    const float* __restrict__ bhh,   // 4096
    f4* __restrict__ slots,          // [2][NSLOT]
    float* __restrict__ hs)          // 8192x1024; write hs[1..T-1]
{
    __shared__ float h_sh[2][HDIM];
    const int g = blockIdx.x, tid = threadIdx.x;
    const int w = tid >> 6, l = tid & 63;
    const int wv = g * 8 + w;
    const int iA = 2 * wv, iB = iA + 1;
    const int rows[6] = { iA, 2*HDIM + iA, 3*HDIM + iA, iB, 2*HDIM + iB, 3*HDIM + iB };

    f4 Wf[6][4];
#pragma unroll
    for (int r = 0; r < 6; ++r) {
        const float* wr = wih + (size_t)rows[r] * HDIM + 4 * l;
#pragma unroll
        for (int j = 0; j < 4; ++j) Wf[r][j] = *(const f4*)(wr + 256 * j);
    }
#pragma unroll
    for (int r = 0; r < 6; ++r)
#pragma unroll
        for (int j = 0; j < 4; ++j)
            asm volatile("" : "+v"(Wf[r][j]));

    float b0 = 0.f, b1 = 0.f, b2 = 0.f;
    int xrow = (l == 0) ? iA : iB;
    if (l < 2) {
        b0 = bih[xrow]          + bhh[xrow];
        b1 = bih[2*HDIM + xrow] + bhh[2*HDIM + xrow];
        b2 = bih[3*HDIM + xrow] + bhh[3*HDIM + xrow];
    }

    for (int s = 1; s < T_STEPS; ++s) {
        const unsigned want = (unsigned)(8191 + s);
        const unsigned pub  = (unsigned)(8192 + s);
        const int buf = (int)(want & 1);
        f4 sa = poll_slot(slots + (size_t)buf * NSLOT + tid, want);
        h_sh[buf][2*tid + 0] = sa.x; h_sh[buf][2*tid + 1] = sa.y;
        __syncthreads();

        f4 h4[4];
#pragma unroll
        for (int j = 0; j < 4; ++j) h4[j] = *(const f4*)&h_sh[buf][256*j + 4*l];

        float red[6];
#pragma unroll
        for (int r = 0; r < 6; ++r) {
            f4 p = Wf[r][0]*h4[0] + Wf[r][1]*h4[1] + Wf[r][2]*h4[2] + Wf[r][3]*h4[3];
            float v = p.x + p.y + p.z + p.w;
#pragma unroll
            for (int off = 32; off > 0; off >>= 1) v += __shfl_xor(v, off, 64);
            red[r] = v;
        }

        float hn = 0.f;
        if (l < 2) {
            float rd0 = (l == 0) ? red[0] : red[3];
            float rd1 = (l == 0) ? red[1] : red[4];
            float rd2 = (l == 0) ? red[2] : red[5];
            float i_ = sigm(rd0 + b0);
            float g_ = tanh_f(rd1 + b1);
            float o_ = sigm(rd2 + b2);
            hn = o_ * tanh_f(i_ * g_);
        }
        float hBv = __shfl(hn, 1, 64);
        if (l == 0) {
            f4 sv; sv.x = hn; sv.y = hBv; sv.z = 0.0f; sv.w = __uint_as_float(pub);
            store_cohr(slots + (size_t)(pub & 1) * NSLOT + wv, sv);
            hs[(size_t)s * HDIM + iA] = hn;
            hs[(size_t)s * HDIM + iB] = hBv;
        }
    }
}

// ---------------------------------------------------------------------------
// Final tiny GEMM: out[t][0:8] = y1[t] @ dec_w2^T + dec_b2, one wave per t
// ---------------------------------------------------------------------------
__global__ __launch_bounds__(256) void dec2_kernel(
    const float* __restrict__ y1,    // 8192x512
    const float* __restrict__ w2,    // 8x512
    const float* __restrict__ b2,    // 8
    float* __restrict__ out)         // 8192x8
{
    const int w = threadIdx.x >> 6, l = threadIdx.x & 63;
    const int t = blockIdx.x * 4 + w;
    const float* yr = y1 + (size_t)t * 512;
    float yv[8];
#pragma unroll
    for (int j = 0; j < 8; ++j) yv[j] = yr[l + 64 * j];
    float o[8];
#pragma unroll
    for (int n = 0; n < 8; ++n) {
        const float* wr = w2 + n * 512;
        float s = 0.f;
#pragma unroll
        for (int j = 0; j < 8; ++j) s += yv[j] * wr[l + 64 * j];
#pragma unroll
        for (int off = 32; off > 0; off >>= 1) s += __shfl_xor(s, off, 64);
        o[n] = s;
    }
    if (l == 0) {
#pragma unroll
        for (int n = 0; n < 8; ++n) out[(size_t)t * 8 + n] = o[n] + b2[n];
    }
}

// ---------------------------------------------------------------------------
extern "C" void kernel_launch(void* const* d_in, const int* in_sizes, int n_in,
                              void* d_out, int out_size, void* d_ws, size_t ws_size,
                              hipStream_t stream)
{
    const float* wea      = (const float*)d_in[0];
    const float* inf      = (const float*)d_in[1];
    const float* h_init   = (const float*)d_in[3];
    const float* enc_w1   = (const float*)d_in[4];
    const float* enc_b1   = (const float*)d_in[5];
    const float* enc_w2   = (const float*)d_in[6];
    const float* enc_b2   = (const float*)d_in[7];
    const float* gru_wih  = (const float*)d_in[8];
    const float* gru_whh  = (const float*)d_in[9];
    const float* gru_bih  = (const float*)d_in[10];
    const float* gru_bhh  = (const float*)d_in[11];
    const float* lstm_wih = (const float*)d_in[12];
    const float* lstm_bih = (const float*)d_in[13];
    const float* lstm_bhh = (const float*)d_in[14];
    const float* dec_w1   = (const float*)d_in[15];
    const float* dec_b1   = (const float*)d_in[16];
    const float* dec_w2   = (const float*)d_in[17];
    const float* dec_b2   = (const float*)d_in[18];

    if (ws_size < WS_NEEDED) return;

    char* ws = (char*)d_ws;
    float* rev   = (float*)(ws + OFF_REV);
    float* x1    = (float*)(ws + OFF_X1);
    float* x2    = (float*)(ws + OFF_B);    // later reused as hs
    float* hs    = (float*)(ws + OFF_B);
    float* xp    = (float*)(ws + OFF_C);    // later reused as y1
    float* y1    = (float*)(ws + OFF_C);
    f4*    slots = (f4*)(ws + OFF_X1);      // x1 is dead after gemm2; 16 KB

    build_rev<<<(T_STEPS * 64) / 256, 256, 0, stream>>>(wea, inf, rev);

    // encoder
    gemm_bias_act<<<dim3(8, 128), 256, 0, stream>>>(rev, enc_w1, enc_b1, x1,
                                                    T_STEPS, 512, 64, 1);
    gemm_bias_act<<<dim3(16, 128), 256, 0, stream>>>(x1, enc_w2, enc_b2, x2,
                                                     T_STEPS, 1024, 512, 1);
    // GRU input projection xp = x2 @ gru_wih^T + gru_bih
    gemm_bias_act<<<dim3(48, 128), 256, 0, stream>>>(x2, gru_wih, gru_bih, xp,
                                                     T_STEPS, 3 * HDIM, HDIM, 0);
    // seed slot buffers (x1 region is now dead) and run the scans
    seed_slots<<<4, 256, 0, stream>>>(h_init, slots);
    gru_scan<<<GW, 512, 0, stream>>>(gru_whh, gru_bhh, xp, slots, hs);
    lstm_scan<<<GW, 512, 0, stream>>>(lstm_wih, lstm_bih, lstm_bhh, slots, hs);

    // decoder
    gemm_bias_act<<<dim3(8, 128), 256, 0, stream>>>(hs, dec_w1, dec_b1, y1,
                                                    T_STEPS, 512, HDIM, 1);
    dec2_kernel<<<T_STEPS / 4, 256, 0, stream>>>(y1, dec_w2, dec_b2, (float*)d_out);
}

// Round 7
// 42080.106 us; speedup vs baseline: 3.4420x; 1.3369x over previous
//
#include <hip/hip_runtime.h>
#include <hip/hip_bf16.h>
#include <math.h>

// Problem constants
#define T_STEPS 8192
#define HDIM    1024
#define GW      128     // workgroups per scan kernel (1 per CU, all co-resident)
#define NSLOT   512     // one slot per wave: 2 h-values + tag
#define SLOT_PITCH 256  // bytes between slots: spread across MALL channels

// Workspace layout (bytes)
#define OFF_REV   ((size_t)0)                         // 8192*64*4   = 2 MB
#define OFF_X1    ((size_t)2097152)                   // 8192*512*4  = 16 MB (reused as slots after gemm2)
#define OFF_B     ((size_t)18874368)                  // x2 then hs: 8192*1024*4 = 32 MB
#define OFF_C     ((size_t)52428800)                  // xp then y1: 8192*3072*4 = 96 MB
#define WS_NEEDED ((size_t)153092096)

typedef float f4 __attribute__((ext_vector_type(4)));

__device__ inline float sigm(float x)   { return 1.0f / (1.0f + __expf(-x)); }
__device__ inline float tanh_f(float x) { float e = __expf(2.0f * x); return 1.0f - 2.0f / (e + 1.0f); }

// slot k of buffer b lives at base + (b*NSLOT + k)*SLOT_PITCH
__device__ inline f4* slot_ptr(char* base, int b, int k) {
    return (f4*)(base + ((size_t)b * NSLOT + k) * SLOT_PITCH);
}

// Device-coherent (L1+L2-bypassing) 16B store: tag travels with data in one
// transaction. MALL is the only working coherence point (R4/R5: remote
// stores never refresh another L2's stale line; sc0-only polling unsound).
__device__ inline void store_cohr(f4* p, f4 v) {
    asm volatile("global_store_dwordx4 %0, %1, off sc0 sc1"
                 :: "v"(p), "v"(v) : "memory");
}

// Paired poll of slots k, k+1 (SLOT_PITCH apart): both loads issued
// back-to-back, ONE wait, both tags checked. s_sleep(1) throttles MALL
// pressure between rounds (R2 lesson: unthrottled polling congests).
__device__ inline void poll_pair(const f4* p, unsigned want, f4& a, f4& b) {
    for (;;) {
        f4 va, vb;
        asm volatile("global_load_dwordx4 %0, %2, off sc0 sc1\n\t"
                     "global_load_dwordx4 %1, %2, off offset:256 sc0 sc1\n\t"
                     "s_waitcnt vmcnt(0)"
                     : "=&v"(va), "=&v"(vb) : "v"(p) : "memory");
        if (__float_as_uint(va.w) == want && __float_as_uint(vb.w) == want) {
            a = va; b = vb; return;
        }
        __builtin_amdgcn_s_sleep(1);
    }
}

// ---------------------------------------------------------------------------
// build rev: rev[t][0:32]=weather[T-1-t], rev[t][32:64]=infect[T-1-t]
// ---------------------------------------------------------------------------
__global__ void build_rev(const float* __restrict__ wea, const float* __restrict__ inf,
                          float* __restrict__ rev) {
    int idx = blockIdx.x * blockDim.x + threadIdx.x;   // over T*64
    if (idx >= T_STEPS * 64) return;
    int t = idx >> 6, c = idx & 63;
    int ts = T_STEPS - 1 - t;
    rev[idx] = (c < 32) ? wea[ts * 32 + c] : inf[ts * 32 + (c - 32)];
}

// ---------------------------------------------------------------------------
// seed slots: buffer 0 with h_init (tag 0), buffer 1 with poison tag
// ---------------------------------------------------------------------------
__global__ void seed_slots(const float* __restrict__ h0, char* __restrict__ sb) {
    int i = blockIdx.x * blockDim.x + threadIdx.x;   // grid covers 2*NSLOT
    if (i < NSLOT) {
        f4 v;
        v.x = h0[2 * i]; v.y = h0[2 * i + 1]; v.z = 0.0f;
        v.w = __uint_as_float(0u);
        store_cohr(slot_ptr(sb, 0, i), v);
    } else if (i < 2 * NSLOT) {
        f4 v;
        v.x = 0.f; v.y = 0.f; v.z = 0.f;
        v.w = __uint_as_float(0xFFFFFFFFu);          // poison tag
        store_cohr(slot_ptr(sb, 0, i), v);           // i in [NSLOT,2*NSLOT) = buffer 1
    }
}

// ---------------------------------------------------------------------------
// Tiled f32 GEMM: C[M,N] = act(A[M,K] @ W[N,K]^T + bias[N]); BM=BN=64, BK=32
// ---------------------------------------------------------------------------
__global__ __launch_bounds__(256) void gemm_bias_act(
    const float* __restrict__ A, const float* __restrict__ W,
    const float* __restrict__ bias, float* __restrict__ C,
    int M, int N, int K, int relu)
{
    __shared__ float As[32][68];
    __shared__ float Ws[32][68];
    const int tid = threadIdx.x;
    const int tx = tid & 15, ty = tid >> 4;
    const int bm = blockIdx.y, bn = blockIdx.x;
    const float* Ab = A + (size_t)bm * 64 * K;
    const float* Wb = W + (size_t)bn * 64 * K;
    float acc[4][4] = {};

    for (int k0 = 0; k0 < K; k0 += 32) {
#pragma unroll
        for (int q = 0; q < 2; ++q) {
            int idx = tid * 2 + q;           // 0..511
            int row = idx >> 3;              // 0..63
            int kc  = (idx & 7) << 2;        // 0..28
            float4 av = *(const float4*)(Ab + (size_t)row * K + k0 + kc);
            As[kc + 0][row] = av.x; As[kc + 1][row] = av.y;
            As[kc + 2][row] = av.z; As[kc + 3][row] = av.w;
            float4 wv = *(const float4*)(Wb + (size_t)row * K + k0 + kc);
            Ws[kc + 0][row] = wv.x; Ws[kc + 1][row] = wv.y;
            Ws[kc + 2][row] = wv.z; Ws[kc + 3][row] = wv.w;
        }
        __syncthreads();
#pragma unroll
        for (int k = 0; k < 32; ++k) {
            float4 a = *(const float4*)&As[k][ty << 2];
            float4 b = *(const float4*)&Ws[k][tx << 2];
            acc[0][0] += a.x*b.x; acc[0][1] += a.x*b.y; acc[0][2] += a.x*b.z; acc[0][3] += a.x*b.w;
            acc[1][0] += a.y*b.x; acc[1][1] += a.y*b.y; acc[1][2] += a.y*b.z; acc[1][3] += a.y*b.w;
            acc[2][0] += a.z*b.x; acc[2][1] += a.z*b.y; acc[2][2] += a.z*b.z; acc[2][3] += a.z*b.w;
            acc[3][0] += a.w*b.x; acc[3][1] += a.w*b.y; acc[3][2] += a.w*b.z; acc[3][3] += a.w*b.w;
        }
        __syncthreads();
    }

    int m0 = bm * 64 + (ty << 2), n0 = bn * 64 + (tx << 2);
    float4 bv = *(const float4*)(bias + n0);
#pragma unroll
    for (int r = 0; r < 4; ++r) {
        float4 o;
        o.x = acc[r][0] + bv.x; o.y = acc[r][1] + bv.y;
        o.z = acc[r][2] + bv.z; o.w = acc[r][3] + bv.w;
        if (relu) {
            o.x = fmaxf(o.x, 0.f); o.y = fmaxf(o.y, 0.f);
            o.z = fmaxf(o.z, 0.f); o.w = fmaxf(o.w, 0.f);
        }
        *(float4*)(C + (size_t)(m0 + r) * N + n0) = o;
    }
}

// ---------------------------------------------------------------------------
// GRU scan. 128 WGs x 256 thr; wave wv=g*4+w owns h[2wv],h[2wv+1].
// Weights pinned in VGPRs (asm touch). Tag-in-data slot protocol, no fences.
// Tags: read tag t from buffer t&1, publish tag t+1 into buffer (t+1)&1.
// Slots are 256B-padded to spread polls/publishes across MALL channels.
// ---------------------------------------------------------------------------
__global__ __launch_bounds__(256, 1) void gru_scan(
    const float* __restrict__ whh,   // 3072x1024
    const float* __restrict__ bhh,   // 3072
    const float* __restrict__ xp,    // 8192x3072 (includes bih)
    char* __restrict__ sb,           // slot base, 2 buffers x NSLOT x 256B
    float* __restrict__ hs)          // 8192x1024; hs[0]=h_enc written at end
{
    __shared__ float h_sh[2][HDIM];
    const int g = blockIdx.x, tid = threadIdx.x;
    const int w = tid >> 6, l = tid & 63;
    const int wv = g * 4 + w;
    const int iA = 2 * wv, iB = iA + 1;
    const int rows[6] = { iA, HDIM + iA, 2*HDIM + iA, iB, HDIM + iB, 2*HDIM + iB };

    // weights -> VGPRs: lane l holds w[row][256j + 4l .. +3]
    f4 Wf[6][4];
#pragma unroll
    for (int r = 0; r < 6; ++r) {
        const float* wr = whh + (size_t)rows[r] * HDIM + 4 * l;
#pragma unroll
        for (int j = 0; j < 4; ++j) Wf[r][j] = *(const f4*)(wr + 256 * j);
    }
#pragma unroll
    for (int r = 0; r < 6; ++r)
#pragma unroll
        for (int j = 0; j < 4; ++j)
            asm volatile("" : "+v"(Wf[r][j]));   // pin: opaque def, cannot remat

    // per-output constants on lanes 0 (output iA) and 1 (output iB)
    float b0 = 0.f, b1 = 0.f, b2 = 0.f;
    float xv0 = 0.f, xv1 = 0.f, xv2 = 0.f;
    int xrow = (l == 0) ? iA : iB;
    if (l < 2) {
        b0 = bhh[xrow]; b1 = bhh[HDIM + xrow]; b2 = bhh[2*HDIM + xrow];
        xv0 = xp[xrow]; xv1 = xp[HDIM + xrow]; xv2 = xp[2*HDIM + xrow];
    }

    for (int t = 0; t < T_STEPS; ++t) {
        const int buf = t & 1;
        // poll the two slots this thread stages (h[4tid..4tid+3]) in ONE wait
        f4 sa, sb2;
        poll_pair(slot_ptr(sb, buf, 2 * tid), (unsigned)t, sa, sb2);
        h_sh[buf][4*tid + 0] = sa.x;  h_sh[buf][4*tid + 1] = sa.y;
        h_sh[buf][4*tid + 2] = sb2.x; h_sh[buf][4*tid + 3] = sb2.y;
        __syncthreads();

        f4 h4[4];
#pragma unroll
        for (int j = 0; j < 4; ++j) h4[j] = *(const f4*)&h_sh[buf][256*j + 4*l];

        float red[6];
#pragma unroll
        for (int r = 0; r < 6; ++r) {
            f4 p = Wf[r][0]*h4[0] + Wf[r][1]*h4[1] + Wf[r][2]*h4[2] + Wf[r][3]*h4[3];
            float v = p.x + p.y + p.z + p.w;
#pragma unroll
            for (int off = 32; off > 0; off >>= 1) v += __shfl_xor(v, off, 64);
            red[r] = v;
        }

        // gate math: lane0 -> output iA, lane1 -> output iB
        float hn = 0.f;
        if (l < 2) {
            float rd0 = (l == 0) ? red[0] : red[3];
            float rd1 = (l == 0) ? red[1] : red[4];
            float rd2 = (l == 0) ? red[2] : red[5];
            float hh_r = rd0 + b0, hh_z = rd1 + b1, hh_n = rd2 + b2;
            float r_ = sigm(xv0 + hh_r);
            float z_ = sigm(xv1 + hh_z);
            float n_ = tanh_f(xv2 + r_ * hh_n);
            float hp = h_sh[buf][xrow];
            hn = (1.0f - z_) * n_ + z_ * hp;
        }
        float hBv = __shfl(hn, 1, 64);
        if (l == 0) {
            unsigned pub = (unsigned)(t + 1);
            f4 s; s.x = hn; s.y = hBv; s.z = 0.0f; s.w = __uint_as_float(pub);
            store_cohr(slot_ptr(sb, (int)(pub & 1), wv), s);
            if (t == T_STEPS - 1) { hs[iA] = hn; hs[iB] = hBv; }
        }
        // prefetch next xp (off critical path; lands during next poll)
        if (l < 2 && t + 1 < T_STEPS) {
            const float* xq = xp + (size_t)(t + 1) * (3 * HDIM);
            xv0 = xq[xrow]; xv1 = xq[HDIM + xrow]; xv2 = xq[2*HDIM + xrow];
        }
    }
}

// ---------------------------------------------------------------------------
// LSTM-like decoder scan: h_new = o*tanh(i*g); forget rows [H,2H) are dead.
// Continues the tag sequence: reads tag 8191+s, publishes 8192+s.
// ---------------------------------------------------------------------------
__global__ __launch_bounds__(256, 1) void lstm_scan(
    const float* __restrict__ wih,   // 4096x1024
    const float* __restrict__ bih,   // 4096
    const float* __restrict__ bhh,   // 4096
    char* __restrict__ sb,           // slot base
    float* __restrict__ hs)          // 8192x1024; write hs[1..T-1]
{
    __shared__ float h_sh[2][HDIM];
    const int g = blockIdx.x, tid = threadIdx.x;
    const int w = tid >> 6, l = tid & 63;
    const int wv = g * 4 + w;
    const int iA = 2 * wv, iB = iA + 1;
    const int rows[6] = { iA, 2*HDIM + iA, 3*HDIM + iA, iB, 2*HDIM + iB, 3*HDIM + iB };

    f4 Wf[6][4];
#pragma unroll
    for (int r = 0; r < 6; ++r) {
        const float* wr = wih + (size_t)rows[r] * HDIM + 4 * l;
#pragma unroll
        for (int j = 0; j < 4; ++j) Wf[r][j] = *(const f4*)(wr + 256 * j);
    }
#pragma unroll
    for (int r = 0; r < 6; ++r)
#pragma unroll
        for (int j = 0; j < 4; ++j)
            asm volatile("" : "+v"(Wf[r][j]));

    float b0 = 0.f, b1 = 0.f, b2 = 0.f;
    int xrow = (l == 0) ? iA : iB;
    if (l < 2) {
        b0 = bih[xrow]          + bhh[xrow];
        b1 = bih[2*HDIM + xrow] + bhh[2*HDIM + xrow];
        b2 = bih[3*HDIM + xrow] + bhh[3*HDIM + xrow];
    }

    for (int s = 1; s < T_STEPS; ++s) {
        const unsigned want = (unsigned)(8191 + s);
        const unsigned pub  = (unsigned)(8192 + s);
        const int buf = (int)(want & 1);
        f4 sa, sb2;
        poll_pair(slot_ptr(sb, buf, 2 * tid), want, sa, sb2);
        h_sh[buf][4*tid + 0] = sa.x;  h_sh[buf][4*tid + 1] = sa.y;
        h_sh[buf][4*tid + 2] = sb2.x; h_sh[buf][4*tid + 3] = sb2.y;
        __syncthreads();

        f4 h4[4];
#pragma unroll
        for (int j = 0; j < 4; ++j) h4[j] = *(const f4*)&h_sh[buf][256*j + 4*l];

        float red[6];
#pragma unroll
        for (int r = 0; r < 6; ++r) {
            f4 p = Wf[r][0]*h4[0] + Wf[r][1]*h4[1] + Wf[r][2]*h4[2] + Wf[r][3]*h4[3];
            float v = p.x + p.y + p.z + p.w;
#pragma unroll
            for (int off = 32; off > 0; off >>= 1) v += __shfl_xor(v, off, 64);
            red[r] = v;
        }

        float hn = 0.f;
        if (l < 2) {
            float rd0 = (l == 0) ? red[0] : red[3];
            float rd1 = (l == 0) ? red[1] : red[4];
            float rd2 = (l == 0) ? red[2] : red[5];
            float i_ = sigm(rd0 + b0);
            float g_ = tanh_f(rd1 + b1);
            float o_ = sigm(rd2 + b2);
            hn = o_ * tanh_f(i_ * g_);
        }
        float hBv = __shfl(hn, 1, 64);
        if (l == 0) {
            f4 sv; sv.x = hn; sv.y = hBv; sv.z = 0.0f; sv.w = __uint_as_float(pub);
            store_cohr(slot_ptr(sb, (int)(pub & 1), wv), sv);
            hs[(size_t)s * HDIM + iA] = hn;
            hs[(size_t)s * HDIM + iB] = hBv;
        }
    }
}

// ---------------------------------------------------------------------------
// Final tiny GEMM: out[t][0:8] = y1[t] @ dec_w2^T + dec_b2, one wave per t
// ---------------------------------------------------------------------------
__global__ __launch_bounds__(256) void dec2_kernel(
    const float* __restrict__ y1,    // 8192x512
    const float* __restrict__ w2,    // 8x512
    const float* __restrict__ b2,    // 8
    float* __restrict__ out)         // 8192x8
{
    const int w = threadIdx.x >> 6, l = threadIdx.x & 63;
    const int t = blockIdx.x * 4 + w;
    const float* yr = y1 + (size_t)t * 512;
    float yv[8];
#pragma unroll
    for (int j = 0; j < 8; ++j) yv[j] = yr[l + 64 * j];
    float o[8];
#pragma unroll
    for (int n = 0; n < 8; ++n) {
        const float* wr = w2 + n * 512;
        float s = 0.f;
#pragma unroll
        for (int j = 0; j < 8; ++j) s += yv[j] * wr[l + 64 * j];
#pragma unroll
        for (int off = 32; off > 0; off >>= 1) s += __shfl_xor(s, off, 64);
        o[n] = s;
    }
    if (l == 0) {
#pragma unroll
        for (int n = 0; n < 8; ++n) out[(size_t)t * 8 + n] = o[n] + b2[n];
    }
}

// ---------------------------------------------------------------------------
extern "C" void kernel_launch(void* const* d_in, const int* in_sizes, int n_in,
                              void* d_out, int out_size, void* d_ws, size_t ws_size,
                              hipStream_t stream)
{
    const float* wea      = (const float*)d_in[0];
    const float* inf      = (const float*)d_in[1];
    const float* h_init   = (const float*)d_in[3];
    const float* enc_w1   = (const float*)d_in[4];
    const float* enc_b1   = (const float*)d_in[5];
    const float* enc_w2   = (const float*)d_in[6];
    const float* enc_b2   = (const float*)d_in[7];
    const float* gru_wih  = (const float*)d_in[8];
    const float* gru_whh  = (const float*)d_in[9];
    const float* gru_bih  = (const float*)d_in[10];
    const float* gru_bhh  = (const float*)d_in[11];
    const float* lstm_wih = (const float*)d_in[12];
    const float* lstm_bih = (const float*)d_in[13];
    const float* lstm_bhh = (const float*)d_in[14];
    const float* dec_w1   = (const float*)d_in[15];
    const float* dec_b1   = (const float*)d_in[16];
    const float* dec_w2   = (const float*)d_in[17];
    const float* dec_b2   = (const float*)d_in[18];

    if (ws_size < WS_NEEDED) return;

    char* ws = (char*)d_ws;
    float* rev   = (float*)(ws + OFF_REV);
    float* x1    = (float*)(ws + OFF_X1);
    float* x2    = (float*)(ws + OFF_B);    // later reused as hs
    float* hs    = (float*)(ws + OFF_B);
    float* xp    = (float*)(ws + OFF_C);    // later reused as y1
    float* y1    = (float*)(ws + OFF_C);
    char*  sb    = ws + OFF_X1;             // slots: 2*512*256B = 256 KB in dead x1

    build_rev<<<(T_STEPS * 64) / 256, 256, 0, stream>>>(wea, inf, rev);

    // encoder
    gemm_bias_act<<<dim3(8, 128), 256, 0, stream>>>(rev, enc_w1, enc_b1, x1,
                                                    T_STEPS, 512, 64, 1);
    gemm_bias_act<<<dim3(16, 128), 256, 0, stream>>>(x1, enc_w2, enc_b2, x2,
                                                     T_STEPS, 1024, 512, 1);
    // GRU input projection xp = x2 @ gru_wih^T + gru_bih
    gemm_bias_act<<<dim3(48, 128), 256, 0, stream>>>(x2, gru_wih, gru_bih, xp,
                                                     T_STEPS, 3 * HDIM, HDIM, 0);
    // seed slot buffers (x1 region is now dead) and run the scans
    seed_slots<<<4, 256, 0, stream>>>(h_init, sb);
    gru_scan<<<GW, 256, 0, stream>>>(gru_whh, gru_bhh, xp, sb, hs);
    lstm_scan<<<GW, 256, 0, stream>>>(lstm_wih, lstm_bih, lstm_bhh, sb, hs);

    // decoder
    gemm_bias_act<<<dim3(8, 128), 256, 0, stream>>>(hs, dec_w1, dec_b1, y1,
                                                    T_STEPS, 512, HDIM, 1);
    dec2_kernel<<<T_STEPS / 4, 256, 0, stream>>>(y1, dec_w2, dec_b2, (float*)d_out);
}